// Round 1
// baseline (98.424 us; speedup 1.0000x reference)
//
#include <hip/hip_runtime.h>
#include <hip/hip_bf16.h>

#ifndef __has_builtin
#define __has_builtin(x) 0
#endif

__device__ __forceinline__ float fast_exp2(float x) {
#if __has_builtin(__builtin_amdgcn_exp2f)
    return __builtin_amdgcn_exp2f(x);   // v_exp_f32, 1 inst
#else
    return exp2f(x);
#endif
}

#define VQ_K 256
#define VQ_D 4

// Table layout in d_ws (floats):
//   [0    .. 1023] c2[k][d] = 2*log2(e) * center[k][d]   (dot operand)
//   [1024 .. 2047] w [k][d] = p_k * center[k][d]         (acc operand)
//   [2048 .. 2303] p [k]    = exp(-||c_k||^2)            (denominator operand)
// Softmax weight = exp2(x . c2_k) * p_k  == exp(||x||^2) * softmax-numerator,
// and the common factors cancel in acc/denom, so out = acc/denom exactly.
__global__ void vq_precompute(const float* __restrict__ center,
                              float* __restrict__ tbl) {
    int k = threadIdx.x;
    if (k < VQ_K) {
        const float L2E = 1.4426950408889634f;
        float c0 = center[k * 4 + 0];
        float c1 = center[k * 4 + 1];
        float c2 = center[k * 4 + 2];
        float c3 = center[k * 4 + 3];
        float csq = c0 * c0 + c1 * c1 + c2 * c2 + c3 * c3;
        float p = fast_exp2(-L2E * csq);          // exp(-csq)
        tbl[k * 4 + 0] = 2.0f * L2E * c0;
        tbl[k * 4 + 1] = 2.0f * L2E * c1;
        tbl[k * 4 + 2] = 2.0f * L2E * c2;
        tbl[k * 4 + 3] = 2.0f * L2E * c3;
        tbl[1024 + k * 4 + 0] = p * c0;
        tbl[1024 + k * 4 + 1] = p * c1;
        tbl[1024 + k * 4 + 2] = p * c2;
        tbl[1024 + k * 4 + 3] = p * c3;
        tbl[2048 + k] = p;
    }
}

// One thread per 4-d vector m. Table read via wave-uniform k -> s_load into
// SGPRs (constant-cache path); inner loop is 9 main-pipe VALU + 1 v_exp_f32.
__global__ __launch_bounds__(256) void vq_main(const float* __restrict__ x,
                                               const float* __restrict__ tbl,
                                               float* __restrict__ out) {
    int m = blockIdx.x * 256 + threadIdx.x;
    float4 xv = reinterpret_cast<const float4*>(x)[m];

    const float* __restrict__ c2 = tbl;
    const float* __restrict__ w  = tbl + 1024;
    const float* __restrict__ pp = tbl + 2048;

    float den = 0.0f;
    float a0 = 0.0f, a1 = 0.0f, a2 = 0.0f, a3 = 0.0f;

#pragma unroll 8
    for (int k = 0; k < VQ_K; ++k) {
        float t = xv.x * c2[4 * k + 0];
        t = fmaf(xv.y, c2[4 * k + 1], t);
        t = fmaf(xv.z, c2[4 * k + 2], t);
        t = fmaf(xv.w, c2[4 * k + 3], t);
        float e = fast_exp2(t);                   // exp(2 x.c_k)
        den = fmaf(e, pp[k], den);
        a0 = fmaf(e, w[4 * k + 0], a0);
        a1 = fmaf(e, w[4 * k + 1], a1);
        a2 = fmaf(e, w[4 * k + 2], a2);
        a3 = fmaf(e, w[4 * k + 3], a3);
    }

    float inv = 1.0f / den;                        // amortized over 256 iters
    float4 o;
    o.x = a0 * inv;
    o.y = a1 * inv;
    o.z = a2 * inv;
    o.w = a3 * inv;
    reinterpret_cast<float4*>(out)[m] = o;
}

extern "C" void kernel_launch(void* const* d_in, const int* in_sizes, int n_in,
                              void* d_out, int out_size, void* d_ws, size_t ws_size,
                              hipStream_t stream) {
    const float* x      = (const float*)d_in[0];   // [8, 262144] fp32
    const float* center = (const float*)d_in[1];   // [256, 4] fp32
    float* out = (float*)d_out;
    float* tbl = (float*)d_ws;                     // 2304 floats = 9216 B

    vq_precompute<<<1, VQ_K, 0, stream>>>(center, tbl);

    int nvec = in_sizes[0] / VQ_D;                 // 524288 vectors
    vq_main<<<nvec / 256, 256, 0, stream>>>(x, tbl, out);
}